// Round 2
// baseline (528.280 us; speedup 1.0000x reference)
//
#include <hip/hip_runtime.h>
#include <cstdint>
#include <cstddef>

// ---------------------------------------------------------------------------
// TokenRoutedMLP on MI355X (gfx950)
// R6: GEMM K-loops converted to 4-buffer ring (BK=32) with counted
// s_waitcnt vmcnt(N) + raw s_barrier — 3 K-steps of global_load_lds in
// flight, vmcnt never drained to 0 in the main loop (T4). s_setprio(1)
// around MFMA cluster (T5). sched_barrier(0) after lgkmcnt wait (rule #18).
// Routing, prep/transpose kernels and XCD swizzle unchanged from R5.
// ---------------------------------------------------------------------------

typedef __attribute__((ext_vector_type(8))) _Float16 half8;
typedef __attribute__((ext_vector_type(4))) float floatx4;

#define AS_G __attribute__((address_space(1)))
#define AS_L __attribute__((address_space(3)))

__device__ __forceinline__ void async_cp16(void* lds, const void* g) {
  __builtin_amdgcn_global_load_lds((const AS_G uint32_t*)g, (AS_L uint32_t*)lds,
                                   16, 0, 0);
}

static constexpr int TTOK = 8192;
static constexpr int DIMK = 2048;
static constexpr int EI = 1024;
static constexpr int NE = 8;
static constexpr int PADT = 9216;
static constexpr int MAXTILES = 80;
static constexpr int NTILE_LAUNCH = 72;

// ------------------------------------------------- routing: hist + tiles ---
__global__ __launch_bounds__(256) void k_route(const int* __restrict__ ids,
                                               int* __restrict__ perm,
                                               int* __restrict__ te,
                                               int* __restrict__ tr0,
                                               int* __restrict__ tnr,
                                               int* __restrict__ cur) {
  __shared__ int cnt[NE];
  __shared__ int sstart[NE];
  __shared__ int snpad[NE];
  __shared__ int stotal;
  int tid = threadIdx.x;
  if (tid < NE) cnt[tid] = 0;
  __syncthreads();
  for (int t = tid; t < TTOK; t += 256) atomicAdd(&cnt[ids[t]], 1);
  __syncthreads();
  if (tid == 0) {
    int pr = 0, nt = 0;
    for (int e = 0; e < NE; e++) {
      int n = cnt[e];
      sstart[e] = pr;
      cur[e] = pr;
      int padded = ((n + 127) >> 7) << 7;
      snpad[e] = padded - n;
      for (int j = 0; j < n; j += 128) {
        te[nt] = e; tr0[nt] = pr + j; tnr[nt] = min(128, n - j); nt++;
      }
      pr += padded;
    }
    stotal = pr;
    for (; nt < MAXTILES; nt++) { te[nt] = 0; tr0[nt] = 0; tnr[nt] = 0; }
  }
  __syncthreads();
  // fill the padding slots of perm (within each expert's range) with token 0
  for (int e = 0; e < NE; e++) {
    int base = sstart[e] + cnt[e];
    for (int i = tid; i < snpad[e]; i += 256) perm[base + i] = 0;
  }
  // fill the unused tail [stotal, PADT) too — k_prep's gather reads it
  for (int i = stotal + tid; i < PADT; i += 256) perm[i] = 0;
}

// -------------------------------------------- routing: parallel scatter ----
__global__ __launch_bounds__(256) void k_scatter(const int* __restrict__ ids,
                                                 int* __restrict__ cur,
                                                 int* __restrict__ perm) {
  __shared__ int bcnt[NE], bbase[NE], bloc[NE];
  int tid = threadIdx.x;
  int t = blockIdx.x * 256 + tid;
  if (tid < NE) { bcnt[tid] = 0; bloc[tid] = 0; }
  __syncthreads();
  int e = ids[t];
  atomicAdd(&bcnt[e], 1);
  __syncthreads();
  if (tid < NE && bcnt[tid] > 0) bbase[tid] = atomicAdd(&cur[tid], bcnt[tid]);
  __syncthreads();
  int off = atomicAdd(&bloc[e], 1);
  perm[bbase[e] + off] = t;
}

// ------------------------------------------- transpose tile (64x64) body ---
template <int K, int N>
__device__ __forceinline__ void transpose_tile(const float* __restrict__ src,
                                               _Float16* __restrict__ dst,
                                               float (*tile)[67], int e,
                                               int n0, int k0, int tid) {
  const float* s = src + (size_t)e * K * N;
  _Float16* d = dst + (size_t)e * N * K;
  int kk = tid >> 4;
  int nn = (tid & 15) * 4;
#pragma unroll
  for (int i = 0; i < 4; i++) {
    float4 v = *(const float4*)(s + (size_t)(k0 + kk + i * 16) * N + n0 + nn);
    tile[kk + i * 16][nn + 0] = v.x;
    tile[kk + i * 16][nn + 1] = v.y;
    tile[kk + i * 16][nn + 2] = v.z;
    tile[kk + i * 16][nn + 3] = v.w;
  }
  __syncthreads();
  int nrow = tid >> 3;
  int k8 = (tid & 7) * 8;
#pragma unroll
  for (int i = 0; i < 2; i++) {
    int n = nrow + i * 32;
    half8 o;
#pragma unroll
    for (int j = 0; j < 8; j++) o[j] = (_Float16)tile[k8 + j][n];
    *(half8*)(d + (size_t)(n0 + n) * K + k0 + k8) = o;
  }
}

// ------------------------- fused: gather x->f16  +  gate_up transpose ------
__global__ __launch_bounds__(256) void k_prep(const float* __restrict__ gup,
                                              _Float16* __restrict__ wt1,
                                              const float* __restrict__ x,
                                              const int* __restrict__ perm,
                                              _Float16* __restrict__ xg) {
  __shared__ float tile[64][67];
  int b = blockIdx.x;
  int tid = threadIdx.x;
  if (b < 8192) {
    int e = b >> 10;
    int r = b & 1023;
    transpose_tile<DIMK, DIMK>(gup, wt1, tile, e, (r & 31) * 64, (r >> 5) * 64,
                               tid);
  } else {
    int row = b - 8192;
    int tok = perm[row];
    int c = tid * 8;
    const float* s = x + (size_t)tok * DIMK + c;
    float4 a = *(const float4*)s;
    float4 bb = *(const float4*)(s + 4);
    half8 o;
    o[0] = (_Float16)a.x; o[1] = (_Float16)a.y;
    o[2] = (_Float16)a.z; o[3] = (_Float16)a.w;
    o[4] = (_Float16)bb.x; o[5] = (_Float16)bb.y;
    o[6] = (_Float16)bb.z; o[7] = (_Float16)bb.w;
    *(half8*)(xg + (size_t)row * DIMK + c) = o;
  }
}

// --------------------------------------------- down-proj transpose ---------
__global__ __launch_bounds__(256) void k_t2(const float* __restrict__ dwn,
                                            _Float16* __restrict__ wt2) {
  __shared__ float tile[64][67];
  transpose_tile<EI, DIMK>(dwn, wt2, tile, blockIdx.z, blockIdx.x * 64,
                           blockIdx.y * 64, threadIdx.x);
}

// --------------------------------------------------------- layer 1 (g,u) ---
// per block: 128 tokens x (64 gate + 64 up cols), K=2048, BK=32, 4-buf ring.
// Counted vmcnt: 4 global_load_lds per buffer per wave, 3 buffers in flight
// -> steady-state wait vmcnt(8) makes current buffer ready. Tail peels 8/4/0.
__global__ __launch_bounds__(256) void k_gateup(
    const _Float16* __restrict__ xg, const _Float16* __restrict__ wt1,
    const int* __restrict__ te, const int* __restrict__ tr0,
    const int* __restrict__ tnr, _Float16* __restrict__ hbuf) {
  int flat = blockIdx.y * 16 + blockIdx.x;
  int swz = (flat & 7) * (NTILE_LAUNCH * 16 / 8) + (flat >> 3);
  int tile = swz >> 4;
  int nr = tnr[tile];
  if (nr == 0) return;
  int e = te[tile], r0 = tr0[tile];
  int col = (swz & 15) * 64;
  int tid = threadIdx.x;

  // per buffer: A 128x32 (8 KB), Bg 64x32 (4 KB), Bu 64x32 (4 KB)
  __shared__ __align__(16) _Float16 As[4][4096];
  __shared__ __align__(16) _Float16 Bg[4][2048];
  __shared__ __align__(16) _Float16 Bu[4][2048];

  int an = tid >> 2;
  int aq = (tid & 3) ^ ((tid >> 3) & 3);
  const _Float16* ap0 = xg + (size_t)(r0 + an) * DIMK + aq * 8;
  const _Float16* ap1 = ap0 + (size_t)64 * DIMK;
  const _Float16* bgp =
      wt1 + (size_t)e * DIMK * DIMK + (size_t)(col + an) * DIMK + aq * 8;
  const _Float16* bup = bgp + (size_t)EI * DIMK;

  int wave = tid >> 6, lane = tid & 63;
  int wm = (wave & 1) * 64, wn = (wave >> 1) * 32;
  int lm = lane & 15, lq = lane >> 4;
  int aoff[4], boff[2];
#pragma unroll
  for (int i = 0; i < 4; i++) {
    int r = wm + i * 16 + lm;
    aoff[i] = (r * 4 + (lq ^ ((r >> 1) & 3))) * 8;
  }
#pragma unroll
  for (int j = 0; j < 2; j++) {
    int n = wn + j * 16 + lm;
    boff[j] = (n * 4 + (lq ^ ((n >> 1) & 3))) * 8;
  }

  floatx4 accg[4][2], accu[4][2];
#pragma unroll
  for (int i = 0; i < 4; i++)
#pragma unroll
    for (int j = 0; j < 2; j++) {
      accg[i][j] = (floatx4)0.0f;
      accu[i][j] = (floatx4)0.0f;
    }

  auto stage = [&](int p, int k0) {  // 4 vmem instructions per wave
    async_cp16(&As[p][(size_t)tid * 8], ap0 + k0);
    async_cp16(&As[p][2048 + (size_t)tid * 8], ap1 + k0);
    async_cp16(&Bg[p][(size_t)tid * 8], bgp + k0);
    async_cp16(&Bu[p][(size_t)tid * 8], bup + k0);
  };

  auto compute = [&](int b) {
    half8 af[4], bgf[2], buf_[2];
#pragma unroll
    for (int i = 0; i < 4; i++) af[i] = *(const half8*)(&As[b][0] + aoff[i]);
#pragma unroll
    for (int j = 0; j < 2; j++) {
      bgf[j] = *(const half8*)(&Bg[b][0] + boff[j]);
      buf_[j] = *(const half8*)(&Bu[b][0] + boff[j]);
    }
    asm volatile("s_waitcnt lgkmcnt(0)" ::: "memory");
    __builtin_amdgcn_sched_barrier(0);
    __builtin_amdgcn_s_setprio(1);
#pragma unroll
    for (int i = 0; i < 4; i++)
#pragma unroll
      for (int j = 0; j < 2; j++) {
        accg[i][j] = __builtin_amdgcn_mfma_f32_16x16x32_f16(
            af[i], bgf[j], accg[i][j], 0, 0, 0);
        accu[i][j] = __builtin_amdgcn_mfma_f32_16x16x32_f16(
            af[i], buf_[j], accu[i][j], 0, 0, 0);
      }
    __builtin_amdgcn_s_setprio(0);
  };

  // prologue: 3 buffers in flight (12 vmem instr outstanding per wave)
  stage(0, 0);
  stage(1, 32);
  stage(2, 64);

  int b = 0;
  // steps 0..60: steady state. Before wait: bufs k,k+1,k+2 outstanding (12).
  // vmcnt(8) -> buf k's 4 loads landed; barrier -> landed for ALL waves and
  // all waves finished reading buf k-1 (their lgkmcnt(0) preceded barrier),
  // so re-staging (b+3)&3 == (k-1)&3 is safe.
  for (int k = 0; k < 61; ++k) {
    asm volatile("s_waitcnt vmcnt(8)" ::: "memory");
    __builtin_amdgcn_s_barrier();
    stage((b + 3) & 3, (k + 3) * 32);
    compute(b);
    b = (b + 1) & 3;
  }
  // k=61: 12 outstanding, no more staging
  asm volatile("s_waitcnt vmcnt(8)" ::: "memory");
  __builtin_amdgcn_s_barrier();
  compute(b);
  b = (b + 1) & 3;
  // k=62
  asm volatile("s_waitcnt vmcnt(4)" ::: "memory");
  __builtin_amdgcn_s_barrier();
  compute(b);
  b = (b + 1) & 3;
  // k=63
  asm volatile("s_waitcnt vmcnt(0)" ::: "memory");
  __builtin_amdgcn_s_barrier();
  compute(b);

#pragma unroll
  for (int i = 0; i < 4; i++) {
    int rbase = wm + i * 16 + lq * 4;
#pragma unroll
    for (int j = 0; j < 2; j++) {
      int c = col + wn + j * 16 + lm;
#pragma unroll
      for (int rr = 0; rr < 4; rr++) {
        float g = accg[i][j][rr];
        float u = accu[i][j][rr];
        float h = g / (1.0f + __expf(-g)) * u;
        hbuf[(size_t)(r0 + rbase + rr) * EI + c] = (_Float16)h;
      }
    }
  }
}

// ------------------------------------------------------------- layer 2 -----
// per block: 128 tokens x 128 out cols, K=1024, BK=32, 4-buf ring.
__global__ __launch_bounds__(256) void k_down(
    const _Float16* __restrict__ hbuf, const _Float16* __restrict__ wt2,
    const int* __restrict__ perm, const int* __restrict__ te,
    const int* __restrict__ tr0, const int* __restrict__ tnr,
    float* __restrict__ out) {
  int flat = blockIdx.y * 16 + blockIdx.x;
  int swz = (flat & 7) * (NTILE_LAUNCH * 16 / 8) + (flat >> 3);
  int tile = swz >> 4;
  int nr = tnr[tile];
  if (nr == 0) return;
  int e = te[tile], r0 = tr0[tile];
  int col = (swz & 15) * 128;
  int tid = threadIdx.x;

  // per buffer: A 128x32 (8 KB), B 128x32 (8 KB)
  __shared__ __align__(16) _Float16 As[4][4096];
  __shared__ __align__(16) _Float16 Bs[4][4096];

  int an = tid >> 2;
  int aq = (tid & 3) ^ ((tid >> 3) & 3);
  const _Float16* ap0 = hbuf + (size_t)(r0 + an) * EI + aq * 8;
  const _Float16* ap1 = ap0 + (size_t)64 * EI;
  const _Float16* wte = wt2 + (size_t)e * DIMK * EI;
  const _Float16* bp0 = wte + (size_t)(col + an) * EI + aq * 8;
  const _Float16* bp1 = bp0 + (size_t)64 * EI;

  int wave = tid >> 6, lane = tid & 63;
  int wm = (wave & 1) * 64, wn = (wave >> 1) * 64;
  int lm = lane & 15, lq = lane >> 4;
  int aoff[4], boff[4];
#pragma unroll
  for (int i = 0; i < 4; i++) {
    int r = wm + i * 16 + lm;
    aoff[i] = (r * 4 + (lq ^ ((r >> 1) & 3))) * 8;
    int n = wn + i * 16 + lm;
    boff[i] = (n * 4 + (lq ^ ((n >> 1) & 3))) * 8;
  }

  floatx4 acc[4][4];
#pragma unroll
  for (int i = 0; i < 4; i++)
#pragma unroll
    for (int j = 0; j < 4; j++) acc[i][j] = (floatx4)0.0f;

  auto stage = [&](int p, int k0) {  // 4 vmem instructions per wave
    async_cp16(&As[p][(size_t)tid * 8], ap0 + k0);
    async_cp16(&As[p][2048 + (size_t)tid * 8], ap1 + k0);
    async_cp16(&Bs[p][(size_t)tid * 8], bp0 + k0);
    async_cp16(&Bs[p][2048 + (size_t)tid * 8], bp1 + k0);
  };

  auto compute = [&](int b) {
    half8 af[4], bf[4];
#pragma unroll
    for (int i = 0; i < 4; i++) {
      af[i] = *(const half8*)(&As[b][0] + aoff[i]);
      bf[i] = *(const half8*)(&Bs[b][0] + boff[i]);
    }
    asm volatile("s_waitcnt lgkmcnt(0)" ::: "memory");
    __builtin_amdgcn_sched_barrier(0);
    __builtin_amdgcn_s_setprio(1);
#pragma unroll
    for (int i = 0; i < 4; i++)
#pragma unroll
      for (int j = 0; j < 4; j++)
        acc[i][j] = __builtin_amdgcn_mfma_f32_16x16x32_f16(af[i], bf[j],
                                                           acc[i][j], 0, 0, 0);
    __builtin_amdgcn_s_setprio(0);
  };

  stage(0, 0);
  stage(1, 32);
  stage(2, 64);

  int b = 0;
  for (int k = 0; k < 29; ++k) {
    asm volatile("s_waitcnt vmcnt(8)" ::: "memory");
    __builtin_amdgcn_s_barrier();
    stage((b + 3) & 3, (k + 3) * 32);
    compute(b);
    b = (b + 1) & 3;
  }
  // k=29
  asm volatile("s_waitcnt vmcnt(8)" ::: "memory");
  __builtin_amdgcn_s_barrier();
  compute(b);
  b = (b + 1) & 3;
  // k=30
  asm volatile("s_waitcnt vmcnt(4)" ::: "memory");
  __builtin_amdgcn_s_barrier();
  compute(b);
  b = (b + 1) & 3;
  // k=31
  asm volatile("s_waitcnt vmcnt(0)" ::: "memory");
  __builtin_amdgcn_s_barrier();
  compute(b);

#pragma unroll
  for (int i = 0; i < 4; i++) {
    int rbase = wm + i * 16 + lq * 4;
#pragma unroll
    for (int rr = 0; rr < 4; rr++) {
      int r = rbase + rr;
      if (r < nr) {
        int tok = perm[r0 + r];
        float* orow = out + (size_t)tok * DIMK + col;
#pragma unroll
        for (int j = 0; j < 4; j++) orow[wn + j * 16 + lm] = acc[i][j][rr];
      }
    }
  }
}

// ---------------------------------------------------------------- launch ---
extern "C" void kernel_launch(void* const* d_in, const int* in_sizes, int n_in,
                              void* d_out, int out_size, void* d_ws,
                              size_t ws_size, hipStream_t stream) {
  const float* x = (const float*)d_in[0];
  const int* ids = (const int*)d_in[1];
  const float* gup = (const float*)d_in[2];
  const float* dwn = (const float*)d_in[3];
  float* out = (float*)d_out;
  char* ws = (char*)d_ws;

  int* perm = (int*)ws;                          // 9216 ints
  int* te = (int*)(ws + 36864);
  int* tr0 = (int*)(ws + 36864 + 512);
  int* tnr = (int*)(ws + 36864 + 1024);
  int* cur = (int*)(ws + 36864 + 1536);          // 8 ints
  _Float16* wt1 = (_Float16*)(ws + 65536);                  // 67,108,864 B
  _Float16* hbuf = (_Float16*)(ws + 65536 + 67108864);      // 18,874,368 B
  _Float16* xg = (_Float16*)(ws + 65536 + 67108864 + 18874368);  // 37,748,736 B
  _Float16* wt2 = wt1;  // aliased; k_t2 runs after k_gateup is done with wt1
  // peak ws = 123,797,504 B

  k_route<<<dim3(1), dim3(256), 0, stream>>>(ids, perm, te, tr0, tnr, cur);
  k_scatter<<<dim3(32), dim3(256), 0, stream>>>(ids, cur, perm);
  k_prep<<<dim3(8192 + PADT), dim3(256), 0, stream>>>(gup, wt1, x, perm, xg);
  k_gateup<<<dim3(16, NTILE_LAUNCH), dim3(256), 0, stream>>>(
      xg, wt1, te, tr0, tnr, hbuf);
  k_t2<<<dim3(32, 16, 8), dim3(256), 0, stream>>>(dwn, wt2);
  k_down<<<dim3(16, NTILE_LAUNCH), dim3(256), 0, stream>>>(
      hbuf, wt2, perm, te, tr0, tnr, out);
}

// Round 3
// 507.144 us; speedup vs baseline: 1.0417x; 1.0417x over previous
//
#include <hip/hip_runtime.h>
#include <cstdint>
#include <cstddef>

// ---------------------------------------------------------------------------
// TokenRoutedMLP on MI355X (gfx950)
// R7: GEMM geometry 128x128/4-wave -> 256x256/8-wave (wave tile 128x64),
// BK=64, 128 KB LDS double-buffer, R5-style single-barrier loop (verified
// structure; p made compile-time by 2x unroll). Gate/up pairing kept inside
// each wave (B rows 0-127 = gate cols, 128-255 = up cols; acc j<2 gate,
// j>=2 up) so silu needs no cross-lane traffic. Routing pads experts to 256
// with 128-tail tiles (PADT stays 9216; workspace layout byte-identical).
// R6's counted-vmcnt ring reverted (measured regression).
// ---------------------------------------------------------------------------

typedef __attribute__((ext_vector_type(8))) _Float16 half8;
typedef __attribute__((ext_vector_type(4))) float floatx4;

#define AS_G __attribute__((address_space(1)))
#define AS_L __attribute__((address_space(3)))

__device__ __forceinline__ void async_cp16(void* lds, const void* g) {
  __builtin_amdgcn_global_load_lds((const AS_G uint32_t*)g, (AS_L uint32_t*)lds,
                                   16, 0, 0);
}

static constexpr int TTOK = 8192;
static constexpr int DIMK = 2048;
static constexpr int EI = 1024;
static constexpr int NE = 8;
static constexpr int PADT = 9216;
static constexpr int MAXTILES = 40;   // sum floor(n/256) <= 32, + <=8 tails
static constexpr int NT_LAUNCH = 40;

// ------------------------------------------------- routing: hist + tiles ---
__global__ __launch_bounds__(256) void k_route(const int* __restrict__ ids,
                                               int* __restrict__ perm,
                                               int* __restrict__ te,
                                               int* __restrict__ tr0,
                                               int* __restrict__ tnr,
                                               int* __restrict__ tts,
                                               int* __restrict__ cur) {
  __shared__ int cnt[NE];
  __shared__ int sstart[NE];
  __shared__ int snpad[NE];
  __shared__ int stotal;
  int tid = threadIdx.x;
  if (tid < NE) cnt[tid] = 0;
  __syncthreads();
  for (int t = tid; t < TTOK; t += 256) atomicAdd(&cnt[ids[t]], 1);
  __syncthreads();
  if (tid == 0) {
    int pr = 0, nt = 0;
    for (int e = 0; e < NE; e++) {
      int n = cnt[e];
      sstart[e] = pr;
      cur[e] = pr;
      int full = n >> 8, rem = n & 255;
      for (int j = 0; j < full; j++) {
        te[nt] = e; tr0[nt] = pr + j * 256; tnr[nt] = 256; tts[nt] = 256; nt++;
      }
      int padded = full * 256;
      if (rem) {
        int tsz = (rem <= 128) ? 128 : 256;
        te[nt] = e; tr0[nt] = pr + padded; tnr[nt] = rem; tts[nt] = tsz; nt++;
        padded += tsz;
      }
      snpad[e] = padded - n;
      pr += padded;
    }
    stotal = pr;
    for (; nt < MAXTILES; nt++) { te[nt] = 0; tr0[nt] = 0; tnr[nt] = 0; tts[nt] = 128; }
  }
  __syncthreads();
  // fill the padding slots of perm (within each expert's range) with token 0
  for (int e = 0; e < NE; e++) {
    int base = sstart[e] + cnt[e];
    for (int i = tid; i < snpad[e]; i += 256) perm[base + i] = 0;
  }
  // fill the unused tail [stotal, PADT) too — k_prep's gather reads it
  for (int i = stotal + tid; i < PADT; i += 256) perm[i] = 0;
}

// -------------------------------------------- routing: parallel scatter ----
__global__ __launch_bounds__(256) void k_scatter(const int* __restrict__ ids,
                                                 int* __restrict__ cur,
                                                 int* __restrict__ perm) {
  __shared__ int bcnt[NE], bbase[NE], bloc[NE];
  int tid = threadIdx.x;
  int t = blockIdx.x * 256 + tid;
  if (tid < NE) { bcnt[tid] = 0; bloc[tid] = 0; }
  __syncthreads();
  int e = ids[t];
  atomicAdd(&bcnt[e], 1);
  __syncthreads();
  if (tid < NE && bcnt[tid] > 0) bbase[tid] = atomicAdd(&cur[tid], bcnt[tid]);
  __syncthreads();
  int off = atomicAdd(&bloc[e], 1);
  perm[bbase[e] + off] = t;
}

// ------------------------------------------- transpose tile (64x64) body ---
template <int K, int N>
__device__ __forceinline__ void transpose_tile(const float* __restrict__ src,
                                               _Float16* __restrict__ dst,
                                               float (*tile)[67], int e,
                                               int n0, int k0, int tid) {
  const float* s = src + (size_t)e * K * N;
  _Float16* d = dst + (size_t)e * N * K;
  int kk = tid >> 4;
  int nn = (tid & 15) * 4;
#pragma unroll
  for (int i = 0; i < 4; i++) {
    float4 v = *(const float4*)(s + (size_t)(k0 + kk + i * 16) * N + n0 + nn);
    tile[kk + i * 16][nn + 0] = v.x;
    tile[kk + i * 16][nn + 1] = v.y;
    tile[kk + i * 16][nn + 2] = v.z;
    tile[kk + i * 16][nn + 3] = v.w;
  }
  __syncthreads();
  int nrow = tid >> 3;
  int k8 = (tid & 7) * 8;
#pragma unroll
  for (int i = 0; i < 2; i++) {
    int n = nrow + i * 32;
    half8 o;
#pragma unroll
    for (int j = 0; j < 8; j++) o[j] = (_Float16)tile[k8 + j][n];
    *(half8*)(d + (size_t)(n0 + n) * K + k0 + k8) = o;
  }
}

// ------------------------- fused: gather x->f16  +  gate_up transpose ------
__global__ __launch_bounds__(256) void k_prep(const float* __restrict__ gup,
                                              _Float16* __restrict__ wt1,
                                              const float* __restrict__ x,
                                              const int* __restrict__ perm,
                                              _Float16* __restrict__ xg) {
  __shared__ float tile[64][67];
  int b = blockIdx.x;
  int tid = threadIdx.x;
  if (b < 8192) {
    int e = b >> 10;
    int r = b & 1023;
    transpose_tile<DIMK, DIMK>(gup, wt1, tile, e, (r & 31) * 64, (r >> 5) * 64,
                               tid);
  } else {
    int row = b - 8192;
    int tok = perm[row];
    int c = tid * 8;
    const float* s = x + (size_t)tok * DIMK + c;
    float4 a = *(const float4*)s;
    float4 bb = *(const float4*)(s + 4);
    half8 o;
    o[0] = (_Float16)a.x; o[1] = (_Float16)a.y;
    o[2] = (_Float16)a.z; o[3] = (_Float16)a.w;
    o[4] = (_Float16)bb.x; o[5] = (_Float16)bb.y;
    o[6] = (_Float16)bb.z; o[7] = (_Float16)bb.w;
    *(half8*)(xg + (size_t)row * DIMK + c) = o;
  }
}

// --------------------------------------------- down-proj transpose ---------
__global__ __launch_bounds__(256) void k_t2(const float* __restrict__ dwn,
                                            _Float16* __restrict__ wt2) {
  __shared__ float tile[64][67];
  transpose_tile<EI, DIMK>(dwn, wt2, tile, blockIdx.z, blockIdx.x * 64,
                           blockIdx.y * 64, threadIdx.x);
}

// --------------------------------------------------------- layer 1 (g,u) ---
// per block: 256 tokens x (128 gate + 128 up cols), 8 waves, wave 128x64.
// K=2048, BK=64, LDS 128 KB (2 buf x (A 32KB + B 32KB)).
__global__ __launch_bounds__(512, 1) void k_gu(
    const _Float16* __restrict__ xg, const _Float16* __restrict__ wt1,
    const int* __restrict__ te, const int* __restrict__ tr0,
    const int* __restrict__ tnr, const int* __restrict__ tts,
    _Float16* __restrict__ hbuf) {
  // bijective XCD swizzle: nwg = 8*40 = 320 = 8*40; cb fastest within swz so
  // one XCD runs all 8 col-blocks of a token tile (A reuse in its L2).
  int flat = blockIdx.y * 8 + blockIdx.x;
  int swz = (flat & 7) * NT_LAUNCH + (flat >> 3);
  int tile = swz >> 3, cb = swz & 7;
  int nr = tnr[tile];
  if (nr == 0) return;
  int e = te[tile], r0 = tr0[tile], tsz = tts[tile];
  int tid = threadIdx.x;

  // per buffer: 2 slabs(K-32) x 256 rows x 4 slots x 8 halfs = 16384 halfs
  __shared__ __align__(16) _Float16 As[2][16384];
  __shared__ __align__(16) _Float16 Bs[2][16384];

  int arow = tid >> 2;              // 0..127
  int slot = tid & 3;
  int cg = (slot ^ ((arow >> 1) & 3)) * 8;  // swizzled K-chunk (halfs)
  int arow1 = (tsz == 256) ? 128 + arow : arow;  // clamp for 128-tail tiles
  const _Float16* apA = xg + (size_t)(r0 + arow) * DIMK;
  const _Float16* apB = xg + (size_t)(r0 + arow1) * DIMK;
  const _Float16* wte = wt1 + (size_t)e * DIMK * DIMK;
  const _Float16* bpG = wte + (size_t)(cb * 128 + arow) * DIMK;
  const _Float16* bpU = wte + (size_t)(EI + cb * 128 + arow) * DIMK;

  auto stage = [&](int p, int k0) {  // 8 gload_lds per thread
#pragma unroll
    for (int s = 0; s < 2; s++) {
      int go = k0 + s * 32 + cg;
      _Float16* al = &As[p][s * 8192 + tid * 8];
      _Float16* bl = &Bs[p][s * 8192 + tid * 8];
      async_cp16(al, apA + go);
      async_cp16(al + 4096, apB + go);
      async_cp16(bl, bpG + go);
      async_cp16(bl + 4096, bpU + go);
    }
  };

  int wave = tid >> 6;
  int wr = wave >> 2, wc = wave & 3;
  int lane = tid & 63, lm = lane & 15, lq = lane >> 4;
  int aoff[8], boff[4];
#pragma unroll
  for (int i = 0; i < 8; i++) {
    int r = wr * 128 + i * 16 + lm;
    aoff[i] = (r * 4 + (lq ^ ((r >> 1) & 3))) * 8;
  }
#pragma unroll
  for (int j = 0; j < 4; j++) {
    int br = (j < 2) ? (wc * 32 + j * 16 + lm)
                     : (128 + wc * 32 + (j - 2) * 16 + lm);
    boff[j] = (br * 4 + (lq ^ ((br >> 1) & 3))) * 8;
  }

  floatx4 acc[8][4];
#pragma unroll
  for (int i = 0; i < 8; i++)
#pragma unroll
    for (int j = 0; j < 4; j++) acc[i][j] = (floatx4)0.0f;

  auto compute = [&](int p) {
#pragma unroll
    for (int s = 0; s < 2; s++) {
      const _Float16* Ab = &As[p][s * 8192];
      const _Float16* Bb = &Bs[p][s * 8192];
      half8 af[8], bf[4];
#pragma unroll
      for (int i = 0; i < 8; i++) af[i] = *(const half8*)(Ab + aoff[i]);
#pragma unroll
      for (int j = 0; j < 4; j++) bf[j] = *(const half8*)(Bb + boff[j]);
#pragma unroll
      for (int i = 0; i < 8; i++)
#pragma unroll
        for (int j = 0; j < 4; j++)
          acc[i][j] = __builtin_amdgcn_mfma_f32_16x16x32_f16(af[i], bf[j],
                                                             acc[i][j], 0, 0, 0);
    }
  };

  stage(0, 0);
  __syncthreads();
  for (int k0 = 0; k0 < DIMK; k0 += 128) {
    if (k0 + 64 < DIMK) stage(1, k0 + 64);
    compute(0);
    __syncthreads();
    if (k0 + 128 < DIMK) stage(0, k0 + 128);
    compute(1);
    __syncthreads();
  }

#pragma unroll
  for (int i = 0; i < 8; i++) {
    int rl0 = wr * 128 + i * 16;
    if (rl0 >= tsz) continue;  // 128-tail tiles: skip wr=1 rows
#pragma unroll
    for (int j = 0; j < 2; j++) {
      int c = cb * 128 + wc * 32 + j * 16 + lm;
#pragma unroll
      for (int rr = 0; rr < 4; rr++) {
        float g = acc[i][j][rr];
        float u = acc[i][j + 2][rr];
        float h = g / (1.0f + __expf(-g)) * u;
        hbuf[(size_t)(r0 + rl0 + lq * 4 + rr) * EI + c] = (_Float16)h;
      }
    }
  }
}

// ------------------------------------------------------------- layer 2 -----
// per block: 256 tokens x 256 out cols, 8 waves, wave 128x64. K=1024, BK=64.
__global__ __launch_bounds__(512, 1) void k_dn(
    const _Float16* __restrict__ hbuf, const _Float16* __restrict__ wt2,
    const int* __restrict__ perm, const int* __restrict__ te,
    const int* __restrict__ tr0, const int* __restrict__ tnr,
    const int* __restrict__ tts, float* __restrict__ out) {
  int flat = blockIdx.y * 8 + blockIdx.x;
  int swz = (flat & 7) * NT_LAUNCH + (flat >> 3);
  int tile = swz >> 3, cb = swz & 7;
  int nr = tnr[tile];
  if (nr == 0) return;
  int e = te[tile], r0 = tr0[tile], tsz = tts[tile];
  int tid = threadIdx.x;

  __shared__ __align__(16) _Float16 As[2][16384];
  __shared__ __align__(16) _Float16 Bs[2][16384];

  int arow = tid >> 2;
  int slot = tid & 3;
  int cg = (slot ^ ((arow >> 1) & 3)) * 8;
  int arow1 = (tsz == 256) ? 128 + arow : arow;
  const _Float16* apA = hbuf + (size_t)(r0 + arow) * EI;
  const _Float16* apB = hbuf + (size_t)(r0 + arow1) * EI;
  const _Float16* wte = wt2 + (size_t)e * DIMK * EI;
  const _Float16* bp0 = wte + (size_t)(cb * 256 + arow) * EI;
  const _Float16* bp1 = wte + (size_t)(cb * 256 + 128 + arow) * EI;

  auto stage = [&](int p, int k0) {
#pragma unroll
    for (int s = 0; s < 2; s++) {
      int go = k0 + s * 32 + cg;
      _Float16* al = &As[p][s * 8192 + tid * 8];
      _Float16* bl = &Bs[p][s * 8192 + tid * 8];
      async_cp16(al, apA + go);
      async_cp16(al + 4096, apB + go);
      async_cp16(bl, bp0 + go);
      async_cp16(bl + 4096, bp1 + go);
    }
  };

  int wave = tid >> 6;
  int wr = wave >> 2, wc = wave & 3;
  int lane = tid & 63, lm = lane & 15, lq = lane >> 4;
  int aoff[8], boff[4];
#pragma unroll
  for (int i = 0; i < 8; i++) {
    int r = wr * 128 + i * 16 + lm;
    aoff[i] = (r * 4 + (lq ^ ((r >> 1) & 3))) * 8;
  }
#pragma unroll
  for (int j = 0; j < 4; j++) {
    int br = wc * 64 + j * 16 + lm;
    boff[j] = (br * 4 + (lq ^ ((br >> 1) & 3))) * 8;
  }

  floatx4 acc[8][4];
#pragma unroll
  for (int i = 0; i < 8; i++)
#pragma unroll
    for (int j = 0; j < 4; j++) acc[i][j] = (floatx4)0.0f;

  auto compute = [&](int p) {
#pragma unroll
    for (int s = 0; s < 2; s++) {
      const _Float16* Ab = &As[p][s * 8192];
      const _Float16* Bb = &Bs[p][s * 8192];
      half8 af[8], bf[4];
#pragma unroll
      for (int i = 0; i < 8; i++) af[i] = *(const half8*)(Ab + aoff[i]);
#pragma unroll
      for (int j = 0; j < 4; j++) bf[j] = *(const half8*)(Bb + boff[j]);
#pragma unroll
      for (int i = 0; i < 8; i++)
#pragma unroll
        for (int j = 0; j < 4; j++)
          acc[i][j] = __builtin_amdgcn_mfma_f32_16x16x32_f16(af[i], bf[j],
                                                             acc[i][j], 0, 0, 0);
    }
  };

  stage(0, 0);
  __syncthreads();
  for (int k0 = 0; k0 < EI; k0 += 128) {
    if (k0 + 64 < EI) stage(1, k0 + 64);
    compute(0);
    __syncthreads();
    if (k0 + 128 < EI) stage(0, k0 + 128);
    compute(1);
    __syncthreads();
  }

#pragma unroll
  for (int i = 0; i < 8; i++) {
    int rl0 = wr * 128 + i * 16;
#pragma unroll
    for (int rr = 0; rr < 4; rr++) {
      int r = rl0 + lq * 4 + rr;
      if (r < nr) {
        int tok = perm[r0 + r];
        float* orow = out + (size_t)tok * DIMK + cb * 256;
#pragma unroll
        for (int j = 0; j < 4; j++) orow[wc * 64 + j * 16 + lm] = acc[i][j][rr];
      }
    }
  }
}

// ---------------------------------------------------------------- launch ---
extern "C" void kernel_launch(void* const* d_in, const int* in_sizes, int n_in,
                              void* d_out, int out_size, void* d_ws,
                              size_t ws_size, hipStream_t stream) {
  const float* x = (const float*)d_in[0];
  const int* ids = (const int*)d_in[1];
  const float* gup = (const float*)d_in[2];
  const float* dwn = (const float*)d_in[3];
  float* out = (float*)d_out;
  char* ws = (char*)d_ws;

  int* perm = (int*)ws;                          // 9216 ints = 36864 B
  int* te = (int*)(ws + 36864);
  int* tr0 = (int*)(ws + 37376);
  int* tnr = (int*)(ws + 37888);
  int* tts = (int*)(ws + 38400);
  int* cur = (int*)(ws + 38912);                 // 8 ints
  _Float16* wt1 = (_Float16*)(ws + 65536);                  // 67,108,864 B
  _Float16* hbuf = (_Float16*)(ws + 65536 + 67108864);      // 18,874,368 B
  _Float16* xg = (_Float16*)(ws + 65536 + 67108864 + 18874368);  // 37,748,736 B
  _Float16* wt2 = wt1;  // aliased; k_t2 runs after k_gu is done with wt1
  // peak ws = 123,797,504 B (unchanged)

  k_route<<<dim3(1), dim3(256), 0, stream>>>(ids, perm, te, tr0, tnr, tts, cur);
  k_scatter<<<dim3(32), dim3(256), 0, stream>>>(ids, cur, perm);
  k_prep<<<dim3(8192 + PADT), dim3(256), 0, stream>>>(gup, wt1, x, perm, xg);
  k_gu<<<dim3(8, NT_LAUNCH), dim3(512), 0, stream>>>(
      xg, wt1, te, tr0, tnr, tts, hbuf);
  k_t2<<<dim3(32, 16, 8), dim3(256), 0, stream>>>(dwn, wt2);
  k_dn<<<dim3(8, NT_LAUNCH), dim3(512), 0, stream>>>(
      hbuf, wt2, perm, te, tr0, tnr, tts, out);
}